// Round 1
// baseline (7815.264 us; speedup 1.0000x reference)
//
#include <hip/hip_runtime.h>
#include <hip/hip_bf16.h>
#include <cstdint>

// ---------------------------------------------------------------------------
// MolGraphEncoder: 3x GCNConv(+self-loops, sym-norm) -> gate softmax pool -> proj
// Strategy: build CSR once per call (count/scan/fill), then per layer do
// aggregate-then-transform fused kernel (LDS tile aggregation + K-split GEMM).
// ---------------------------------------------------------------------------

__global__ void k_count(const int* __restrict__ dst, int* __restrict__ cnt, int E) {
    int e = blockIdx.x * blockDim.x + threadIdx.x;
    if (e < E) atomicAdd(&cnt[dst[e]], 1);
}

__global__ void k_dis(const int* __restrict__ cnt, float* __restrict__ dis, int n) {
    int i = blockIdx.x * blockDim.x + threadIdx.x;
    if (i < n) dis[i] = rsqrtf((float)cnt[i] + 1.0f);  // +1 self-loop, deg>=1 always
}

// --- exclusive-scan machinery (2048 items per block) -----------------------
__global__ void k_scan1(const int* __restrict__ in, int* __restrict__ out1 /*rowstart+1*/,
                        int* __restrict__ bsum, int n) {
    __shared__ int s[256];
    int t = threadIdx.x;
    int base = blockIdx.x * 2048 + t * 8;
    int v[8];
    int run = 0;
#pragma unroll
    for (int i = 0; i < 8; ++i) {
        int idx = base + i;
        int x = (idx < n) ? in[idx] : 0;
        run += x;
        v[i] = run;
    }
    s[t] = run;
    __syncthreads();
    for (int off = 1; off < 256; off <<= 1) {
        int add = (t >= off) ? s[t - off] : 0;
        __syncthreads();
        s[t] += add;
        __syncthreads();
    }
    int pre = (t > 0) ? s[t - 1] : 0;
#pragma unroll
    for (int i = 0; i < 8; ++i) {
        int idx = base + i;
        if (idx < n) out1[idx] = v[i] + pre;
    }
    if (t == 255) bsum[blockIdx.x] = s[255];
}

__global__ void k_scan2(int* bsum, int nb) {
    __shared__ int s[256];
    int t = threadIdx.x;
    s[t] = (t < nb) ? bsum[t] : 0;
    __syncthreads();
    for (int off = 1; off < 256; off <<= 1) {
        int add = (t >= off) ? s[t - off] : 0;
        __syncthreads();
        s[t] += add;
        __syncthreads();
    }
    if (t < nb) bsum[t] = s[t];
}

__global__ void k_scan3(int* __restrict__ rowstart, const int* __restrict__ bsum, int n) {
    int b = blockIdx.x, t = threadIdx.x;
    if (b == 0) {
        if (t == 0) rowstart[0] = 0;
        return;
    }
    int add = bsum[b - 1];
    int* out1 = rowstart + 1;
    int base = b * 2048 + t * 8;
#pragma unroll
    for (int i = 0; i < 8; ++i) {
        int idx = base + i;
        if (idx < n) out1[idx] += add;
    }
}

__global__ void k_fill(const int* __restrict__ src, const int* __restrict__ dst,
                       int* __restrict__ cursor, int* __restrict__ csr_src,
                       int* __restrict__ csr_dst, int E) {
    int e = blockIdx.x * blockDim.x + threadIdx.x;
    if (e >= E) return;
    int d = dst[e];
    int pos = atomicAdd(&cursor[d], 1);
    csr_src[pos] = src[e];
    csr_dst[pos] = d;
}

// --- fused GCN layer: aggregate 32-node tile into LDS, then K-split GEMM ----
// out_v = relu( dis[v] * (sum_{u->v} dis[u]*h[u] + dis[v]*h[v]) @ W + b )
template <int F, bool GATE>
__global__ __launch_bounds__(512) void k_gcn(
    const float* __restrict__ hprev, const float* __restrict__ W,
    const float* __restrict__ bias, const float* __restrict__ dis,
    const int* __restrict__ rowstart, const int* __restrict__ csr_src,
    const int* __restrict__ csr_dst, float* __restrict__ hnext,
    const float* __restrict__ gw, const float* __restrict__ gb,
    float* __restrict__ gate, int n) {
    constexpr int KH = (F + 1) / 2;  // K-split half (64 or 41)
    __shared__ float Ws[KH * 128];
    __shared__ float aggs[32 * F];
    int t = threadIdx.x;
    int j = t & 127;   // phase-A feature column
    int q = t >> 7;    // 0..3 edge group
    int jj = t & 63;   // lane
    int j0 = jj * 2;   // phase-B column pair
    int g8 = t >> 6;   // 0..7 node group (4 nodes each)
    float bj0 = bias[j0], bj1 = bias[j0 + 1];
    float gw0 = 0.f, gw1 = 0.f, gbv = 0.f;
    if (GATE) { gw0 = gw[j0]; gw1 = gw[j0 + 1]; gbv = gb[0]; }

    for (int tile = blockIdx.x * 32; tile < n; tile += gridDim.x * 32) {
        __syncthreads();  // aggs safe vs previous tile's reads
        // phase A: self term init
#pragma unroll
        for (int i = 0; i < 8; ++i) {
            int nn = q * 8 + i;
            int v = tile + nn;
            if (j < F) {
                float val = 0.f;
                if (v < n) val = dis[v] * hprev[(size_t)v * F + j];
                aggs[nn * F + j] = val;
            }
        }
        __syncthreads();
        // phase A: edge-parallel gather + LDS atomic accumulate
        int thi = (tile + 32 > n) ? n : tile + 32;
        int elo = rowstart[tile];
        int ehi = rowstart[thi];
        for (int e = elo + q; e < ehi; e += 4) {
            int u = csr_src[e];
            int nn = csr_dst[e] - tile;
            if (j < F) atomicAdd(&aggs[nn * F + j], dis[u] * hprev[(size_t)u * F + j]);
        }
        // phase B: K-split GEMM (keeps static LDS <= 48KB)
        float acc[4][2];
#pragma unroll
        for (int i = 0; i < 4; ++i) { acc[i][0] = 0.f; acc[i][1] = 0.f; }
#pragma unroll
        for (int half = 0; half < 2; ++half) {
            const int k0 = half ? KH : 0;
            const int kn = half ? (F - KH) : KH;
            __syncthreads();  // aggs ready / prev half's Ws reads done
            for (int i = t; i < kn * 32; i += 512)
                ((float4*)Ws)[i] = ((const float4*)(W + k0 * 128))[i];
            __syncthreads();
            for (int k = 0; k < kn; ++k) {
                float2 w = *(const float2*)&Ws[k * 128 + j0];
#pragma unroll
                for (int i = 0; i < 4; ++i) {
                    float a = aggs[(g8 * 4 + i) * F + k0 + k];
                    acc[i][0] = fmaf(a, w.x, acc[i][0]);
                    acc[i][1] = fmaf(a, w.y, acc[i][1]);
                }
            }
        }
        // epilogue: scale by dis[v], bias, relu, (optional) fused gate dot
#pragma unroll
        for (int i = 0; i < 4; ++i) {
            int nn = g8 * 4 + i;
            int v = tile + nn;
            if (v < n) {
                float dv = dis[v];
                float o0 = fmaxf(fmaf(acc[i][0], dv, bj0), 0.f);
                float o1 = fmaxf(fmaf(acc[i][1], dv, bj1), 0.f);
                *(float2*)&hnext[(size_t)v * 128 + j0] = make_float2(o0, o1);
                if (GATE) {
                    float gp = o0 * gw0 + o1 * gw1;
#pragma unroll
                    for (int off = 32; off; off >>= 1) gp += __shfl_down(gp, off);
                    if (jj == 0) gate[v] = gp + gbv;
                }
            }
        }
    }
}

// --- graph boundaries on sorted batch via binary search ---------------------
__global__ void k_bounds(const int* __restrict__ batch, int* __restrict__ goff,
                         int n, int B) {
    int g = blockIdx.x * blockDim.x + threadIdx.x;
    if (g > B) return;
    int lo = 0, hi = n;
    while (lo < hi) {
        int mid = (lo + hi) >> 1;
        if (batch[mid] < g) lo = mid + 1;
        else hi = mid;
    }
    goff[g] = lo;
}

// --- attention pooling: one wave per graph ----------------------------------
__global__ __launch_bounds__(256) void k_pool(const float* __restrict__ h,
                                              const float* __restrict__ gate,
                                              const int* __restrict__ goff,
                                              float* __restrict__ emb, int B) {
    int wid = (blockIdx.x * blockDim.x + threadIdx.x) >> 6;
    int lane = threadIdx.x & 63;
    if (wid >= B) return;
    int s = goff[wid], e2 = goff[wid + 1];
    if (s >= e2) {
        emb[(size_t)wid * 128 + lane] = 0.f;
        emb[(size_t)wid * 128 + 64 + lane] = 0.f;
        return;
    }
    float m = -INFINITY;
    for (int v = s + lane; v < e2; v += 64) m = fmaxf(m, gate[v]);
#pragma unroll
    for (int off = 32; off; off >>= 1) m = fmaxf(m, __shfl_xor(m, off));
    float a0 = 0.f, a1 = 0.f, den = 0.f;
    for (int v = s; v < e2; ++v) {
        float ev = expf(gate[v] - m);
        den += ev;
        a0 += ev * h[(size_t)v * 128 + lane];
        a1 += ev * h[(size_t)v * 128 + 64 + lane];
    }
    float inv = 1.f / den;
    emb[(size_t)wid * 128 + lane] = a0 * inv;
    emb[(size_t)wid * 128 + 64 + lane] = a1 * inv;
}

// --- final projection: out = emb @ proj_w + proj_b --------------------------
__global__ __launch_bounds__(256) void k_proj(const float* __restrict__ emb,
                                              const float* __restrict__ pw,
                                              const float* __restrict__ pb,
                                              float* __restrict__ out, int B) {
    __shared__ float es[8][128];
    int g0 = blockIdx.x * 8;
    int t = threadIdx.x;
    for (int i = t; i < 8 * 128; i += 256) {
        int g = g0 + (i >> 7);
        es[i >> 7][i & 127] = (g < B) ? emb[(size_t)g * 128 + (i & 127)] : 0.f;
    }
    __syncthreads();
    float acc[8];
#pragma unroll
    for (int i = 0; i < 8; ++i) acc[i] = 0.f;
    for (int k = 0; k < 128; ++k) {
        float w = pw[k * 256 + t];
#pragma unroll
        for (int i = 0; i < 8; ++i) acc[i] = fmaf(es[i][k], w, acc[i]);
    }
    float b = pb[t];
#pragma unroll
    for (int i = 0; i < 8; ++i) {
        int g = g0 + i;
        if (g < B) out[(size_t)g * 256 + t] = acc[i] + b;
    }
}

// ---------------------------------------------------------------------------
extern "C" void kernel_launch(void* const* d_in, const int* in_sizes, int n_in,
                              void* d_out, int out_size, void* d_ws, size_t ws_size,
                              hipStream_t stream) {
    const float* x = (const float*)d_in[0];
    const int* ei = (const int*)d_in[1];
    const int* batch = (const int*)d_in[2];
    const float* W0 = (const float*)d_in[3];
    const float* b0 = (const float*)d_in[4];
    const float* W1 = (const float*)d_in[5];
    const float* b1 = (const float*)d_in[6];
    const float* W2 = (const float*)d_in[7];
    const float* b2 = (const float*)d_in[8];
    const float* gw = (const float*)d_in[9];
    const float* gb = (const float*)d_in[10];
    const float* pw = (const float*)d_in[11];
    const float* pb = (const float*)d_in[12];
    float* out = (float*)d_out;

    const int N = in_sizes[2];
    const int E = in_sizes[1] / 2;
    const int B = out_size / 256;
    const int F_IN = in_sizes[0] / N;  // 82
    (void)F_IN; (void)n_in;

    const int* esrc = ei;
    const int* edst = ei + E;

    // workspace carve (256B aligned)
    char* p = (char*)d_ws;
    auto carve = [&](size_t bytes) {
        char* r = p;
        p += (bytes + 255) & ~(size_t)255;
        return r;
    };
    float* h1 = (float*)carve((size_t)N * 128 * 4);
    float* h2 = (float*)carve((size_t)N * 128 * 4);
    float* emb = (float*)carve((size_t)B * 128 * 4);
    int* csr_src = (int*)carve((size_t)E * 4);
    int* csr_dst = (int*)carve((size_t)E * 4);
    float* dis = (float*)carve((size_t)N * 4);
    int* cnt = (int*)carve((size_t)N * 4);
    int* rowstart = (int*)carve((size_t)(N + 1) * 4);
    int* cursor = (int*)carve((size_t)N * 4);
    float* gate = (float*)carve((size_t)N * 4);
    int* goff = (int*)carve((size_t)(B + 1) * 4);
    int* bsum = (int*)carve((size_t)4096 * 4);
    if ((size_t)(p - (char*)d_ws) > ws_size) return;  // insufficient workspace

    const int nb = (N + 2047) / 2048;  // 245

    // degree + dis
    hipMemsetAsync(cnt, 0, (size_t)N * 4, stream);
    k_count<<<(E + 255) / 256, 256, 0, stream>>>(edst, cnt, E);
    k_dis<<<(N + 255) / 256, 256, 0, stream>>>(cnt, dis, N);
    // CSR: scan counts -> rowstart, fill
    k_scan1<<<nb, 256, 0, stream>>>(cnt, rowstart + 1, bsum, N);
    k_scan2<<<1, 256, 0, stream>>>(bsum, nb);
    k_scan3<<<nb, 256, 0, stream>>>(rowstart, bsum, N);
    hipMemcpyAsync(cursor, rowstart, (size_t)N * 4, hipMemcpyDeviceToDevice, stream);
    k_fill<<<(E + 255) / 256, 256, 0, stream>>>(esrc, edst, cursor, csr_src, csr_dst, E);

    // 3 GCN layers (ping-pong h1/h2), gate fused into layer 2
    k_gcn<82, false><<<2048, 512, 0, stream>>>(x, W0, b0, dis, rowstart, csr_src,
                                               csr_dst, h1, nullptr, nullptr, nullptr, N);
    k_gcn<128, false><<<2048, 512, 0, stream>>>(h1, W1, b1, dis, rowstart, csr_src,
                                                csr_dst, h2, nullptr, nullptr, nullptr, N);
    k_gcn<128, true><<<2048, 512, 0, stream>>>(h2, W2, b2, dis, rowstart, csr_src,
                                               csr_dst, h1, gw, gb, gate, N);

    // pooling + projection
    k_bounds<<<(B + 1 + 255) / 256, 256, 0, stream>>>(batch, goff, N, B);
    k_pool<<<(B + 3) / 4, 256, 0, stream>>>(h1, gate, goff, emb, B);
    k_proj<<<(B + 7) / 8, 256, 0, stream>>>(emb, pw, pb, out, B);
}

// Round 2
// 1724.506 us; speedup vs baseline: 4.5319x; 4.5319x over previous
//
#include <hip/hip_runtime.h>
#include <hip/hip_bf16.h>
#include <cstdint>

// ---------------------------------------------------------------------------
// MolGraphEncoder: 3x GCNConv(+self-loops, sym-norm) -> gate softmax pool -> proj
// Round 2: split each layer into (1) node-parallel CSR aggregation (wave/node,
// register accum) and (2) LDS-tiled tall-skinny GEMM (A-tile broadcast reads).
// ---------------------------------------------------------------------------

__global__ void k_count(const int* __restrict__ dst, int* __restrict__ cnt, int E) {
    int e = blockIdx.x * blockDim.x + threadIdx.x;
    if (e < E) atomicAdd(&cnt[dst[e]], 1);
}

__global__ void k_dis(const int* __restrict__ cnt, float* __restrict__ dis, int n) {
    int i = blockIdx.x * blockDim.x + threadIdx.x;
    if (i < n) dis[i] = rsqrtf((float)cnt[i] + 1.0f);  // +1 self-loop => deg>=1
}

// --- exclusive-scan machinery (2048 items per block) -----------------------
__global__ void k_scan1(const int* __restrict__ in, int* __restrict__ out1,
                        int* __restrict__ bsum, int n) {
    __shared__ int s[256];
    int t = threadIdx.x;
    int base = blockIdx.x * 2048 + t * 8;
    int v[8];
    int run = 0;
#pragma unroll
    for (int i = 0; i < 8; ++i) {
        int idx = base + i;
        int x = (idx < n) ? in[idx] : 0;
        run += x;
        v[i] = run;
    }
    s[t] = run;
    __syncthreads();
    for (int off = 1; off < 256; off <<= 1) {
        int add = (t >= off) ? s[t - off] : 0;
        __syncthreads();
        s[t] += add;
        __syncthreads();
    }
    int pre = (t > 0) ? s[t - 1] : 0;
#pragma unroll
    for (int i = 0; i < 8; ++i) {
        int idx = base + i;
        if (idx < n) out1[idx] = v[i] + pre;
    }
    if (t == 255) bsum[blockIdx.x] = s[255];
}

__global__ void k_scan2(int* bsum, int nb) {
    __shared__ int s[256];
    int t = threadIdx.x;
    s[t] = (t < nb) ? bsum[t] : 0;
    __syncthreads();
    for (int off = 1; off < 256; off <<= 1) {
        int add = (t >= off) ? s[t - off] : 0;
        __syncthreads();
        s[t] += add;
        __syncthreads();
    }
    if (t < nb) bsum[t] = s[t];
}

__global__ void k_scan3(int* __restrict__ rowstart, const int* __restrict__ bsum, int n) {
    int b = blockIdx.x, t = threadIdx.x;
    if (b == 0) {
        if (t == 0) rowstart[0] = 0;
        return;
    }
    int add = bsum[b - 1];
    int* out1 = rowstart + 1;
    int base = b * 2048 + t * 8;
#pragma unroll
    for (int i = 0; i < 8; ++i) {
        int idx = base + i;
        if (idx < n) out1[idx] += add;
    }
}

__global__ void k_fill(const int* __restrict__ src, const int* __restrict__ dst,
                       int* __restrict__ cursor, int* __restrict__ csr_src, int E) {
    int e = blockIdx.x * blockDim.x + threadIdx.x;
    if (e >= E) return;
    int d = dst[e];
    int pos = atomicAdd(&cursor[d], 1);
    csr_src[pos] = src[e];
}

// --- aggregation: one wave per node, lane-per-column, register accum --------
// agg[v] = dis[v] * ( sum_{u->v} dis[u]*h[u]  +  dis[v]*h[v] )
template <int F>
__global__ __launch_bounds__(256) void k_agg(
    const float* __restrict__ h, const float* __restrict__ dis,
    const int* __restrict__ rowstart, const int* __restrict__ csr_src,
    float* __restrict__ agg, int n) {
    int wid = (blockIdx.x * blockDim.x + threadIdx.x) >> 6;
    int lane = threadIdx.x & 63;
    int nw = (gridDim.x * blockDim.x) >> 6;
    const int c0 = lane, c1 = lane + 64;
    const bool has1 = (c1 < F);
    for (int v = wid; v < n; v += nw) {
        float dv = dis[v];
        const float* hv = h + (size_t)v * F;
        float a0 = dv * hv[c0];
        float a1 = has1 ? dv * hv[c1] : 0.f;
        int e0 = rowstart[v], e1 = rowstart[v + 1];
        for (int e = e0; e < e1; ++e) {
            int u = csr_src[e];
            float du = dis[u];
            const float* hu = h + (size_t)u * F;
            a0 += du * hu[c0];
            if (has1) a1 += du * hu[c1];
        }
        agg[(size_t)v * F + c0] = dv * a0;
        if (has1) agg[(size_t)v * F + c1] = dv * a1;
    }
}

// --- tall-skinny GEMM: out = relu(A @ W + b), A-tile in LDS (broadcast reads)
// A: n x K (row-major), W: K x 128, out: n x 128. Optional fused gate dot.
template <int K, bool GATE>
__global__ __launch_bounds__(512) void k_gemm(
    const float* __restrict__ A, const float* __restrict__ W,
    const float* __restrict__ bias, float* __restrict__ out,
    const float* __restrict__ gw, const float* __restrict__ gb,
    float* __restrict__ gate, int n) {
    __shared__ float As[128 * K];
    int t = threadIdx.x;
    int tile = blockIdx.x * 128;
    int rows = n - tile;
    if (rows > 128) rows = 128;
    const float* src = A + (size_t)tile * K;
    int total = rows * K;
    if constexpr ((K % 4) == 0) {
        for (int i = t; i < total / 4; i += 512) ((float4*)As)[i] = ((const float4*)src)[i];
    } else {
        for (int i = t; i < total / 2; i += 512) ((float2*)As)[i] = ((const float2*)src)[i];
    }
    __syncthreads();

    int jp = t & 63, j0 = jp * 2, mg = t >> 6;  // wave == mg (16 rows per wave)
    float2 bb = *(const float2*)&bias[j0];
    float gwv0 = 0.f, gwv1 = 0.f, gbv = 0.f;
    if (GATE) { gwv0 = gw[j0]; gwv1 = gw[j0 + 1]; gbv = gb[0]; }

    float acc[16][2];
#pragma unroll
    for (int i = 0; i < 16; ++i) { acc[i][0] = 0.f; acc[i][1] = 0.f; }

    for (int k = 0; k < K; k += 2) {
        float2 w0 = *(const float2*)&W[k * 128 + j0];
        float2 w1 = *(const float2*)&W[(k + 1) * 128 + j0];
#pragma unroll
        for (int i = 0; i < 16; ++i) {
            float2 a = *(const float2*)&As[(mg * 16 + i) * K + k];
            acc[i][0] = fmaf(a.x, w0.x, acc[i][0]);
            acc[i][1] = fmaf(a.x, w0.y, acc[i][1]);
            acc[i][0] = fmaf(a.y, w1.x, acc[i][0]);
            acc[i][1] = fmaf(a.y, w1.y, acc[i][1]);
        }
    }

#pragma unroll
    for (int i = 0; i < 16; ++i) {
        int v = tile + mg * 16 + i;
        if (v < n) {
            float o0 = fmaxf(acc[i][0] + bb.x, 0.f);
            float o1 = fmaxf(acc[i][1] + bb.y, 0.f);
            *(float2*)&out[(size_t)v * 128 + j0] = make_float2(o0, o1);
            if (GATE) {
                float gp = o0 * gwv0 + o1 * gwv1;
#pragma unroll
                for (int off = 32; off; off >>= 1) gp += __shfl_xor(gp, off);
                if (jp == 0) gate[v] = gp + gbv;
            }
        }
    }
}

// --- graph boundaries on sorted batch via binary search ---------------------
__global__ void k_bounds(const int* __restrict__ batch, int* __restrict__ goff,
                         int n, int B) {
    int g = blockIdx.x * blockDim.x + threadIdx.x;
    if (g > B) return;
    int lo = 0, hi = n;
    while (lo < hi) {
        int mid = (lo + hi) >> 1;
        if (batch[mid] < g) lo = mid + 1;
        else hi = mid;
    }
    goff[g] = lo;
}

// --- attention pooling: one wave per graph ----------------------------------
__global__ __launch_bounds__(256) void k_pool(const float* __restrict__ h,
                                              const float* __restrict__ gate,
                                              const int* __restrict__ goff,
                                              float* __restrict__ emb, int B) {
    int wid = (blockIdx.x * blockDim.x + threadIdx.x) >> 6;
    int lane = threadIdx.x & 63;
    if (wid >= B) return;
    int s = goff[wid], e2 = goff[wid + 1];
    if (s >= e2) {
        emb[(size_t)wid * 128 + lane] = 0.f;
        emb[(size_t)wid * 128 + 64 + lane] = 0.f;
        return;
    }
    float m = -INFINITY;
    for (int v = s + lane; v < e2; v += 64) m = fmaxf(m, gate[v]);
#pragma unroll
    for (int off = 32; off; off >>= 1) m = fmaxf(m, __shfl_xor(m, off));
    float a0 = 0.f, a1 = 0.f, den = 0.f;
    for (int v = s; v < e2; ++v) {
        float ev = expf(gate[v] - m);
        den += ev;
        a0 += ev * h[(size_t)v * 128 + lane];
        a1 += ev * h[(size_t)v * 128 + 64 + lane];
    }
    float inv = 1.f / den;
    emb[(size_t)wid * 128 + lane] = a0 * inv;
    emb[(size_t)wid * 128 + 64 + lane] = a1 * inv;
}

// --- final projection: out = emb @ proj_w + proj_b --------------------------
__global__ __launch_bounds__(256) void k_proj(const float* __restrict__ emb,
                                              const float* __restrict__ pw,
                                              const float* __restrict__ pb,
                                              float* __restrict__ out, int B) {
    __shared__ float es[8][128];
    int g0 = blockIdx.x * 8;
    int t = threadIdx.x;
    for (int i = t; i < 8 * 128; i += 256) {
        int g = g0 + (i >> 7);
        es[i >> 7][i & 127] = (g < B) ? emb[(size_t)g * 128 + (i & 127)] : 0.f;
    }
    __syncthreads();
    float acc[8];
#pragma unroll
    for (int i = 0; i < 8; ++i) acc[i] = 0.f;
    for (int k = 0; k < 128; ++k) {
        float w = pw[k * 256 + t];
#pragma unroll
        for (int i = 0; i < 8; ++i) acc[i] = fmaf(es[i][k], w, acc[i]);
    }
    float b = pb[t];
#pragma unroll
    for (int i = 0; i < 8; ++i) {
        int g = g0 + i;
        if (g < B) out[(size_t)g * 256 + t] = acc[i] + b;
    }
}

// ---------------------------------------------------------------------------
extern "C" void kernel_launch(void* const* d_in, const int* in_sizes, int n_in,
                              void* d_out, int out_size, void* d_ws, size_t ws_size,
                              hipStream_t stream) {
    const float* x = (const float*)d_in[0];
    const int* ei = (const int*)d_in[1];
    const int* batch = (const int*)d_in[2];
    const float* W0 = (const float*)d_in[3];
    const float* b0 = (const float*)d_in[4];
    const float* W1 = (const float*)d_in[5];
    const float* b1 = (const float*)d_in[6];
    const float* W2 = (const float*)d_in[7];
    const float* b2 = (const float*)d_in[8];
    const float* gw = (const float*)d_in[9];
    const float* gb = (const float*)d_in[10];
    const float* pw = (const float*)d_in[11];
    const float* pb = (const float*)d_in[12];
    float* out = (float*)d_out;

    const int N = in_sizes[2];
    const int E = in_sizes[1] / 2;
    const int B = out_size / 256;
    (void)n_in;

    const int* esrc = ei;
    const int* edst = ei + E;

    // workspace carve (256B aligned)
    char* p = (char*)d_ws;
    auto carve = [&](size_t bytes) {
        char* r = p;
        p += (bytes + 255) & ~(size_t)255;
        return r;
    };
    float* h1 = (float*)carve((size_t)N * 128 * 4);
    float* h2 = (float*)carve((size_t)N * 128 * 4);
    float* emb = (float*)carve((size_t)B * 128 * 4);
    int* csr_src = (int*)carve((size_t)E * 4);
    float* dis = (float*)carve((size_t)N * 4);
    int* cnt = (int*)carve((size_t)N * 4);
    int* rowstart = (int*)carve((size_t)(N + 1) * 4);
    int* cursor = (int*)carve((size_t)N * 4);
    float* gate = (float*)carve((size_t)N * 4);
    int* goff = (int*)carve((size_t)(B + 1) * 4);
    int* bsum = (int*)carve((size_t)4096 * 4);
    if ((size_t)(p - (char*)d_ws) > ws_size) return;

    const int nb = (N + 2047) / 2048;

    // degree + dis
    hipMemsetAsync(cnt, 0, (size_t)N * 4, stream);
    k_count<<<(E + 255) / 256, 256, 0, stream>>>(edst, cnt, E);
    k_dis<<<(N + 255) / 256, 256, 0, stream>>>(cnt, dis, N);
    // CSR: scan counts -> rowstart, fill
    k_scan1<<<nb, 256, 0, stream>>>(cnt, rowstart + 1, bsum, N);
    k_scan2<<<1, 256, 0, stream>>>(bsum, nb);
    k_scan3<<<nb, 256, 0, stream>>>(rowstart, bsum, N);
    hipMemcpyAsync(cursor, rowstart, (size_t)N * 4, hipMemcpyDeviceToDevice, stream);
    k_fill<<<(E + 255) / 256, 256, 0, stream>>>(esrc, edst, cursor, csr_src, E);

    const int gemm_blocks = (N + 127) / 128;

    // layer 0: agg(x) -> h2 (N x 82), gemm -> h1 (N x 128)
    k_agg<82><<<2048, 256, 0, stream>>>(x, dis, rowstart, csr_src, h2, N);
    k_gemm<82, false><<<gemm_blocks, 512, 0, stream>>>(h2, W0, b0, h1,
                                                       nullptr, nullptr, nullptr, N);
    // layer 1: agg(h1) -> h2, gemm -> h1
    k_agg<128><<<2048, 256, 0, stream>>>(h1, dis, rowstart, csr_src, h2, N);
    k_gemm<128, false><<<gemm_blocks, 512, 0, stream>>>(h2, W1, b1, h1,
                                                        nullptr, nullptr, nullptr, N);
    // layer 2: agg(h1) -> h2, gemm(+gate) -> h1
    k_agg<128><<<2048, 256, 0, stream>>>(h1, dis, rowstart, csr_src, h2, N);
    k_gemm<128, true><<<gemm_blocks, 512, 0, stream>>>(h2, W2, b2, h1,
                                                       gw, gb, gate, N);

    // pooling + projection
    k_bounds<<<(B + 1 + 255) / 256, 256, 0, stream>>>(batch, goff, N, B);
    k_pool<<<(B + 3) / 4, 256, 0, stream>>>(h1, gate, goff, emb, B);
    k_proj<<<(B + 7) / 8, 256, 0, stream>>>(emb, pw, pb, out, B);
}

// Round 3
// 913.355 us; speedup vs baseline: 8.5567x; 1.8881x over previous
//
#include <hip/hip_runtime.h>
#include <hip/hip_bf16.h>
#include <cstdint>

// ---------------------------------------------------------------------------
// MolGraphEncoder r3: bf16 activations + MFMA GEMMs.
// agg (bf16 row-sum, dis folded into prev epilogue) -> mfma GEMM (W pre-packed
// into B-fragment layout) -> pool -> proj.
// ---------------------------------------------------------------------------

typedef __attribute__((ext_vector_type(8))) short short8;
typedef __attribute__((ext_vector_type(4))) float f32x4;

__device__ __forceinline__ float b2f(unsigned int hi16) {  // bits<<16 already
    return __builtin_bit_cast(float, hi16);
}
__device__ __forceinline__ unsigned short f2b(float f) {  // RTN-even
    unsigned int u = __builtin_bit_cast(unsigned int, f);
    unsigned int lsb = (u >> 16) & 1u;
    u += 0x7fffu + lsb;
    return (unsigned short)(u >> 16);
}

__global__ void k_count(const int* __restrict__ dst, int* __restrict__ cnt, int E) {
    int e = blockIdx.x * blockDim.x + threadIdx.x;
    if (e < E) atomicAdd(&cnt[dst[e]], 1);
}

__global__ void k_dis(const int* __restrict__ cnt, float* __restrict__ dis, int n) {
    int i = blockIdx.x * blockDim.x + threadIdx.x;
    if (i < n) dis[i] = rsqrtf((float)cnt[i] + 1.0f);  // +1 self-loop => deg>=1
}

// --- exclusive-scan machinery (2048 items per block) -----------------------
__global__ void k_scan1(const int* __restrict__ in, int* __restrict__ out1,
                        int* __restrict__ bsum, int n) {
    __shared__ int s[256];
    int t = threadIdx.x;
    int base = blockIdx.x * 2048 + t * 8;
    int v[8];
    int run = 0;
#pragma unroll
    for (int i = 0; i < 8; ++i) {
        int idx = base + i;
        int x = (idx < n) ? in[idx] : 0;
        run += x;
        v[i] = run;
    }
    s[t] = run;
    __syncthreads();
    for (int off = 1; off < 256; off <<= 1) {
        int add = (t >= off) ? s[t - off] : 0;
        __syncthreads();
        s[t] += add;
        __syncthreads();
    }
    int pre = (t > 0) ? s[t - 1] : 0;
#pragma unroll
    for (int i = 0; i < 8; ++i) {
        int idx = base + i;
        if (idx < n) out1[idx] = v[i] + pre;
    }
    if (t == 255) bsum[blockIdx.x] = s[255];
}

__global__ void k_scan2(int* bsum, int nb) {
    __shared__ int s[256];
    int t = threadIdx.x;
    s[t] = (t < nb) ? bsum[t] : 0;
    __syncthreads();
    for (int off = 1; off < 256; off <<= 1) {
        int add = (t >= off) ? s[t - off] : 0;
        __syncthreads();
        s[t] += add;
        __syncthreads();
    }
    if (t < nb) bsum[t] = s[t];
}

__global__ void k_scan3(int* __restrict__ rowstart, const int* __restrict__ bsum, int n) {
    int b = blockIdx.x, t = threadIdx.x;
    if (b == 0) {
        if (t == 0) rowstart[0] = 0;
        return;
    }
    int add = bsum[b - 1];
    int* out1 = rowstart + 1;
    int base = b * 2048 + t * 8;
#pragma unroll
    for (int i = 0; i < 8; ++i) {
        int idx = base + i;
        if (idx < n) out1[idx] += add;
    }
}

__global__ void k_fill(const int* __restrict__ src, const int* __restrict__ dst,
                       int* __restrict__ cursor, int* __restrict__ csr_src, int E) {
    int e = blockIdx.x * blockDim.x + threadIdx.x;
    if (e >= E) return;
    int d = dst[e];
    int pos = atomicAdd(&cursor[d], 1);
    csr_src[pos] = src[e];
}

// --- pack W (Ksrc x 128 fp32) into MFMA B-fragment layout, bf16, K padded ---
// frag f = m*8+ct; element (f*64+lane)*8+j  <-  W[32m+(lane>>4)*8+j][16ct+(lane&15)]
__global__ void k_cvtw(const float* __restrict__ W, unsigned short* __restrict__ out,
                       int Ksrc, int KS) {
    int tid = blockIdx.x * blockDim.x + threadIdx.x;
    if (tid >= KS * 512) return;
    int lane = tid & 63, f = tid >> 6;
    int m = f >> 3, ct = f & 7;
    int col = ct * 16 + (lane & 15);
    int kb = m * 32 + ((lane >> 4) << 3);
    unsigned short v[8];
#pragma unroll
    for (int j = 0; j < 8; ++j) {
        int k = kb + j;
        v[j] = (k < Ksrc) ? f2b(W[k * 128 + col]) : (unsigned short)0;
    }
    short8* o = (short8*)(out + (size_t)tid * 8);
    *o = *(short8*)v;
}

// --- layer-0 aggregation: x fp32 (82 cols) -> agg bf16 (96 cols, zero-pad) --
__global__ __launch_bounds__(256) void k_agg0(
    const float* __restrict__ x, const float* __restrict__ dis,
    const int* __restrict__ rowstart, const int* __restrict__ csr,
    unsigned short* __restrict__ agg, int n) {
    int wid = (blockIdx.x * blockDim.x + threadIdx.x) >> 6;
    int lane = threadIdx.x & 63;
    int nw = (gridDim.x * blockDim.x) >> 6;
    const int c0 = lane, c1 = lane + 64;
    const bool has1 = (c1 < 82);
    for (int v = wid; v < n; v += nw) {
        float dv = dis[v];
        const float* xv = x + (size_t)v * 82;
        float a0 = dv * xv[c0];
        float a1 = has1 ? dv * xv[c1] : 0.f;
        int e0 = rowstart[v], e1 = rowstart[v + 1];
        for (int e = e0; e < e1; ++e) {
            int u = csr[e];
            float du = dis[u];
            const float* xu = x + (size_t)u * 82;
            a0 += du * xu[c0];
            if (has1) a1 += du * xu[c1];
        }
        unsigned short* av = agg + (size_t)v * 96;
        av[c0] = f2b(dv * a0);
        if (lane < 32) av[64 + lane] = has1 ? f2b(dv * a1) : (unsigned short)0;
    }
}

// --- layers 1/2 aggregation: hd bf16 (dis-prescaled) -> agg bf16 (128 cols) -
// agg[v] = dis[v] * ( hd[v] + sum_{u->v} hd[u] )
__global__ __launch_bounds__(256) void k_aggb(
    const unsigned short* __restrict__ hd, const float* __restrict__ dis,
    const int* __restrict__ rowstart, const int* __restrict__ csr,
    unsigned short* __restrict__ agg, int n) {
    int wid = (blockIdx.x * blockDim.x + threadIdx.x) >> 6;
    int lane = threadIdx.x & 63;
    int nw = (gridDim.x * blockDim.x) >> 6;
    for (int v = wid; v < n; v += nw) {
        unsigned int hv = *(const unsigned int*)((const char*)hd + (size_t)v * 256 + lane * 4);
        float a0 = b2f(hv << 16);
        float a1 = b2f(hv & 0xffff0000u);
        int e0 = rowstart[v], e1 = rowstart[v + 1];
        for (int e = e0; e < e1; ++e) {
            int u = csr[e];
            unsigned int hu = *(const unsigned int*)((const char*)hd + (size_t)u * 256 + lane * 4);
            a0 += b2f(hu << 16);
            a1 += b2f(hu & 0xffff0000u);
        }
        float dv = dis[v];
        unsigned int packed = ((unsigned int)f2b(dv * a1) << 16) | f2b(dv * a0);
        *(unsigned int*)((char*)agg + (size_t)v * 256 + lane * 4) = packed;
    }
}

// --- MFMA GEMM: out(bf16 Nx128) = epi( A(bf16 NxKp) @ Wp + b ) --------------
// wave = 32 rows; SCALE: out *= dis[row] (pre-scale for next agg); GATE: fused dot
template <int Kp, bool SCALE, bool GATE>
__global__ __launch_bounds__(256) void k_mm(
    const unsigned short* __restrict__ A, const unsigned short* __restrict__ Wp,
    const float* __restrict__ bias, const float* __restrict__ dis,
    unsigned short* __restrict__ out, const float* __restrict__ gw,
    const float* __restrict__ gb, float* __restrict__ gate, int n) {
    constexpr int KS = Kp / 32;
    int t = threadIdx.x, lane = t & 63, w = t >> 6;
    int base = blockIdx.x * 128 + w * 32;
    if (base >= n) return;
    int r0 = lane & 15, ch = lane >> 4;
    int row0 = base + r0, row1 = base + 16 + r0;
    if (row0 >= n) row0 = n - 1;
    if (row1 >= n) row1 = n - 1;
    const char* pa0 = (const char*)A + (size_t)row0 * (Kp * 2) + ch * 16;
    const char* pa1 = (const char*)A + (size_t)row1 * (Kp * 2) + ch * 16;

    f32x4 z = {0.f, 0.f, 0.f, 0.f};
    f32x4 acc0[8], acc1[8];
#pragma unroll
    for (int ct = 0; ct < 8; ++ct) { acc0[ct] = z; acc1[ct] = z; }

#pragma unroll
    for (int m = 0; m < KS; ++m) {
        short8 a0 = *(const short8*)(pa0 + m * 64);
        short8 a1 = *(const short8*)(pa1 + m * 64);
        const short8* wf = (const short8*)Wp + (size_t)(m * 8) * 64 + lane;
#pragma unroll
        for (int ct = 0; ct < 8; ++ct) {
            short8 b = wf[ct * 64];
            acc0[ct] = __builtin_amdgcn_mfma_f32_16x16x32_bf16(a0, b, acc0[ct], 0, 0, 0);
            acc1[ct] = __builtin_amdgcn_mfma_f32_16x16x32_bf16(a1, b, acc1[ct], 0, 0, 0);
        }
    }

    int cq = lane & 15;
    float bb[8], gwv[8];
#pragma unroll
    for (int ct = 0; ct < 8; ++ct) {
        bb[ct] = bias[ct * 16 + cq];
        if (GATE) gwv[ct] = gw[ct * 16 + cq];
    }
    float gbv = GATE ? gb[0] : 0.f;

#pragma unroll
    for (int s = 0; s < 2; ++s) {
#pragma unroll
        for (int reg = 0; reg < 4; ++reg) {
            int row = base + s * 16 + ((lane >> 4) << 2) + reg;
            bool ok = row < n;
            float dv = (SCALE && ok) ? dis[row] : 1.f;
            float gp = 0.f;
#pragma unroll
            for (int ct = 0; ct < 8; ++ct) {
                float o = (s == 0) ? acc0[ct][reg] : acc1[ct][reg];
                o = fmaxf(o + bb[ct], 0.f);
                if (GATE) gp = fmaf(o, gwv[ct], gp);
                if (ok) out[(size_t)row * 128 + ct * 16 + cq] = f2b(SCALE ? o * dv : o);
            }
            if (GATE) {
                gp += __shfl_xor(gp, 1);
                gp += __shfl_xor(gp, 2);
                gp += __shfl_xor(gp, 4);
                gp += __shfl_xor(gp, 8);
                if (cq == 0 && ok) gate[row] = gp + gbv;
            }
        }
    }
}

// --- graph boundaries on sorted batch via binary search ---------------------
__global__ void k_bounds(const int* __restrict__ batch, int* __restrict__ goff,
                         int n, int B) {
    int g = blockIdx.x * blockDim.x + threadIdx.x;
    if (g > B) return;
    int lo = 0, hi = n;
    while (lo < hi) {
        int mid = (lo + hi) >> 1;
        if (batch[mid] < g) lo = mid + 1;
        else hi = mid;
    }
    goff[g] = lo;
}

// --- attention pooling: one wave per graph; h is bf16 -----------------------
__global__ __launch_bounds__(256) void k_pool(const unsigned short* __restrict__ h,
                                              const float* __restrict__ gate,
                                              const int* __restrict__ goff,
                                              float* __restrict__ emb, int B) {
    int wid = (blockIdx.x * blockDim.x + threadIdx.x) >> 6;
    int lane = threadIdx.x & 63;
    if (wid >= B) return;
    int s = goff[wid], e2 = goff[wid + 1];
    float* ev2 = emb + (size_t)wid * 128 + lane * 2;
    if (s >= e2) {
        ev2[0] = 0.f;
        ev2[1] = 0.f;
        return;
    }
    float m = -INFINITY;
    for (int v = s + lane; v < e2; v += 64) m = fmaxf(m, gate[v]);
#pragma unroll
    for (int off = 32; off; off >>= 1) m = fmaxf(m, __shfl_xor(m, off));
    float a0 = 0.f, a1 = 0.f, den = 0.f;
    for (int v = s; v < e2; ++v) {
        float ev = __expf(gate[v] - m);
        den += ev;
        unsigned int hv = *(const unsigned int*)((const char*)h + (size_t)v * 256 + lane * 4);
        a0 = fmaf(ev, b2f(hv << 16), a0);
        a1 = fmaf(ev, b2f(hv & 0xffff0000u), a1);
    }
    float inv = 1.f / den;
    ev2[0] = a0 * inv;
    ev2[1] = a1 * inv;
}

// --- final projection: out = emb @ proj_w + proj_b --------------------------
__global__ __launch_bounds__(256) void k_proj(const float* __restrict__ emb,
                                              const float* __restrict__ pw,
                                              const float* __restrict__ pb,
                                              float* __restrict__ out, int B) {
    __shared__ float es[8][128];
    int g0 = blockIdx.x * 8;
    int t = threadIdx.x;
    for (int i = t; i < 8 * 128; i += 256) {
        int g = g0 + (i >> 7);
        es[i >> 7][i & 127] = (g < B) ? emb[(size_t)g * 128 + (i & 127)] : 0.f;
    }
    __syncthreads();
    float acc[8];
#pragma unroll
    for (int i = 0; i < 8; ++i) acc[i] = 0.f;
    for (int k = 0; k < 128; ++k) {
        float w = pw[k * 256 + t];
#pragma unroll
        for (int i = 0; i < 8; ++i) acc[i] = fmaf(es[i][k], w, acc[i]);
    }
    float b = pb[t];
#pragma unroll
    for (int i = 0; i < 8; ++i) {
        int g = g0 + i;
        if (g < B) out[(size_t)g * 256 + t] = acc[i] + b;
    }
}

// ---------------------------------------------------------------------------
extern "C" void kernel_launch(void* const* d_in, const int* in_sizes, int n_in,
                              void* d_out, int out_size, void* d_ws, size_t ws_size,
                              hipStream_t stream) {
    const float* x = (const float*)d_in[0];
    const int* ei = (const int*)d_in[1];
    const int* batch = (const int*)d_in[2];
    const float* W0 = (const float*)d_in[3];
    const float* b0 = (const float*)d_in[4];
    const float* W1 = (const float*)d_in[5];
    const float* b1 = (const float*)d_in[6];
    const float* W2 = (const float*)d_in[7];
    const float* b2 = (const float*)d_in[8];
    const float* gw = (const float*)d_in[9];
    const float* gb = (const float*)d_in[10];
    const float* pw = (const float*)d_in[11];
    const float* pb = (const float*)d_in[12];
    float* out = (float*)d_out;

    const int N = in_sizes[2];
    const int E = in_sizes[1] / 2;
    const int B = out_size / 256;
    (void)n_in;

    const int* esrc = ei;
    const int* edst = ei + E;

    char* p = (char*)d_ws;
    auto carve = [&](size_t bytes) {
        char* r = p;
        p += (bytes + 255) & ~(size_t)255;
        return r;
    };
    unsigned short* hbuf = (unsigned short*)carve((size_t)N * 128 * 2);
    unsigned short* aggbuf = (unsigned short*)carve((size_t)N * 128 * 2);
    float* emb = (float*)carve((size_t)B * 128 * 4);
    int* csr_src = (int*)carve((size_t)E * 4);
    float* dis = (float*)carve((size_t)N * 4);
    int* cnt = (int*)carve((size_t)N * 4);
    int* rowstart = (int*)carve((size_t)(N + 1) * 4);
    int* cursor = (int*)carve((size_t)N * 4);
    float* gate = (float*)carve((size_t)N * 4);
    int* goff = (int*)carve((size_t)(B + 1) * 4);
    int* bsum = (int*)carve((size_t)4096 * 4);
    unsigned short* wp0 = (unsigned short*)carve((size_t)96 * 128 * 2);
    unsigned short* wp1 = (unsigned short*)carve((size_t)128 * 128 * 2);
    unsigned short* wp2 = (unsigned short*)carve((size_t)128 * 128 * 2);
    if ((size_t)(p - (char*)d_ws) > ws_size) return;

    const int nb = (N + 2047) / 2048;

    hipMemsetAsync(cnt, 0, (size_t)N * 4, stream);
    k_count<<<(E + 255) / 256, 256, 0, stream>>>(edst, cnt, E);
    k_dis<<<(N + 255) / 256, 256, 0, stream>>>(cnt, dis, N);
    k_scan1<<<nb, 256, 0, stream>>>(cnt, rowstart + 1, bsum, N);
    k_scan2<<<1, 256, 0, stream>>>(bsum, nb);
    k_scan3<<<nb, 256, 0, stream>>>(rowstart, bsum, N);
    hipMemcpyAsync(cursor, rowstart, (size_t)N * 4, hipMemcpyDeviceToDevice, stream);
    k_fill<<<(E + 255) / 256, 256, 0, stream>>>(esrc, edst, cursor, csr_src, E);

    // pack weights (bf16 fragment layout)
    k_cvtw<<<6, 256, 0, stream>>>(W0, wp0, 82, 3);
    k_cvtw<<<8, 256, 0, stream>>>(W1, wp1, 128, 4);
    k_cvtw<<<8, 256, 0, stream>>>(W2, wp2, 128, 4);

    const int mm_blocks = (N + 127) / 128;

    // layer 0
    k_agg0<<<2048, 256, 0, stream>>>(x, dis, rowstart, csr_src, aggbuf, N);
    k_mm<96, true, false><<<mm_blocks, 256, 0, stream>>>(
        aggbuf, wp0, b0, dis, hbuf, nullptr, nullptr, nullptr, N);
    // layer 1
    k_aggb<<<2048, 256, 0, stream>>>(hbuf, dis, rowstart, csr_src, aggbuf, N);
    k_mm<128, true, false><<<mm_blocks, 256, 0, stream>>>(
        aggbuf, wp1, b1, dis, hbuf, nullptr, nullptr, nullptr, N);
    // layer 2 (unscaled out + fused gate)
    k_aggb<<<2048, 256, 0, stream>>>(hbuf, dis, rowstart, csr_src, aggbuf, N);
    k_mm<128, false, true><<<mm_blocks, 256, 0, stream>>>(
        aggbuf, wp2, b2, dis, hbuf, gw, gb, gate, N);

    // pooling + projection
    k_bounds<<<(B + 1 + 255) / 256, 256, 0, stream>>>(batch, goff, N, B);
    k_pool<<<(B + 3) / 4, 256, 0, stream>>>(hbuf, gate, goff, emb, B);
    k_proj<<<(B + 7) / 8, 256, 0, stream>>>(emb, pw, pb, out, B);
}